// Round 1
// baseline (2818.710 us; speedup 1.0000x reference)
//
#include <hip/hip_runtime.h>

#define E_N 1600000
#define N_N 100000

// d_ws float-offset layout
#define OFF_W0F 0         // 32*64 fused layer0 weights
#define OFF_W1F 2048      // 64*64
#define OFF_W2F 6144      // 64*64
#define OFF_B0F 10240     // 64 fused biases
#define OFF_B1F 10304
#define OFF_B2F 10368
#define OFF_WE0T 10432    // 128*80 transposed end-layer0 weights
#define OFF_Y   20736     // N*80  (cols 0..63 = agg accum, 64..79 = relu(x))
#define OFF_CNT 8020736   // N
// total = 8,120,736 floats = 32.5 MB of d_ws

static __device__ __forceinline__ float b2f(unsigned short u) {
  union { unsigned int i; float f; } c; c.i = ((unsigned int)u) << 16; return c.f;
}
static __device__ __forceinline__ unsigned short f2b(float f) {
  union { float f; unsigned int i; } c; c.f = f;
  unsigned int r = c.i + 0x7FFFu + ((c.i >> 16) & 1u);  // round-nearest-even
  return (unsigned short)(r >> 16);
}

__global__ void prep_kernel(
    const float* __restrict__ w0, const float* __restrict__ b0, const float* __restrict__ g0,
    const float* __restrict__ be0, const float* __restrict__ m0, const float* __restrict__ v0,
    const float* __restrict__ w1, const float* __restrict__ b1, const float* __restrict__ g1,
    const float* __restrict__ be1, const float* __restrict__ m1, const float* __restrict__ v1,
    const float* __restrict__ w2, const float* __restrict__ b2, const float* __restrict__ g2,
    const float* __restrict__ be2, const float* __restrict__ m2, const float* __restrict__ v2,
    const float* __restrict__ we0, float* __restrict__ ws) {
  __shared__ float s0[64], s1[64], s2[64];
  int t = threadIdx.x;
  if (t < 64) {
    s0[t] = g0[t] * rsqrtf(v0[t] + 1e-5f);
    s1[t] = g1[t] * rsqrtf(v1[t] + 1e-5f);
    s2[t] = g2[t] * rsqrtf(v2[t] + 1e-5f);
  }
  __syncthreads();
  for (int i = t; i < 2048; i += 256) ws[OFF_W0F + i] = w0[i] * s0[i & 63];
  for (int i = t; i < 4096; i += 256) ws[OFF_W1F + i] = w1[i] * s1[i & 63];
  for (int i = t; i < 4096; i += 256) ws[OFF_W2F + i] = w2[i] * s2[i & 63];
  if (t < 64) {
    ws[OFF_B0F + t] = (b0[t] - m0[t]) * s0[t] + be0[t];
    ws[OFF_B1F + t] = (b1[t] - m1[t]) * s1[t] + be1[t];
    ws[OFF_B2F + t] = (b2[t] - m2[t]) * s2[t] + be2[t];
  }
  for (int i = t; i < 10240; i += 256) {
    int j = i / 80, k = i - j * 80;
    ws[OFF_WE0T + i] = we0[k * 128 + j];  // we0t[j][k] = we0[k][j]
  }
}

// One MLP layer: in/out activations in per-wave LDS tiles [feature][lane], stride 66.
// Weights via wave-uniform indices -> scalar loads (s_load_dwordx4), VALU does only FMAs.
static __device__ void mlp_layer(const unsigned short* Ain, unsigned short* Aout,
                                 const float* __restrict__ w, const float* __restrict__ b,
                                 int K, int lane) {
  float acc[64];
  const float4* b4 = (const float4*)b;
#pragma unroll
  for (int q = 0; q < 16; ++q) {
    float4 t = b4[q];
    acc[4 * q + 0] = t.x; acc[4 * q + 1] = t.y; acc[4 * q + 2] = t.z; acc[4 * q + 3] = t.w;
  }
  for (int k = 0; k < K; ++k) {
    float a = b2f(Ain[k * 66 + lane]);
    const float4* w4 = (const float4*)(w + (k << 6));
#pragma unroll
    for (int q = 0; q < 16; ++q) {
      float4 wv = w4[q];
      acc[4 * q + 0] = fmaf(a, wv.x, acc[4 * q + 0]);
      acc[4 * q + 1] = fmaf(a, wv.y, acc[4 * q + 1]);
      acc[4 * q + 2] = fmaf(a, wv.z, acc[4 * q + 2]);
      acc[4 * q + 3] = fmaf(a, wv.w, acc[4 * q + 3]);
    }
  }
#pragma unroll
  for (int j = 0; j < 64; ++j) Aout[j * 66 + lane] = f2b(fmaxf(acc[j], 0.f));
}

__global__ __launch_bounds__(128) void edge_inner_kernel(
    const float* __restrict__ x, const int* __restrict__ ei,
    const float* __restrict__ wf, float* __restrict__ y, float* __restrict__ cnt) {
  // per-wave LDS activation tiles, bf16, padded stride 66 (transpose read = conflict-free)
  __shared__ unsigned short A[2][64 * 66];
  __shared__ unsigned short B[2][64 * 66];
  __shared__ int dsts[128];
  const int tid = threadIdx.x;
  const int w = tid >> 6;
  const int lane = tid & 63;
  unsigned short* Aw = A[w];
  unsigned short* Bw = B[w];

  const int e = blockIdx.x * 128 + tid;  // E_N % 128 == 0
  const int src = ei[e];
  const int dst = ei[E_N + e];
  dsts[tid] = dst;

  const float4* x4 = (const float4*)x;
  float4 xi0 = x4[dst * 4 + 0], xi1 = x4[dst * 4 + 1], xi2 = x4[dst * 4 + 2], xi3 = x4[dst * 4 + 3];
  float4 xj0 = x4[src * 4 + 0], xj1 = x4[src * 4 + 1], xj2 = x4[src * 4 + 2], xj3 = x4[src * 4 + 3];
  float vi[16] = {xi0.x, xi0.y, xi0.z, xi0.w, xi1.x, xi1.y, xi1.z, xi1.w,
                  xi2.x, xi2.y, xi2.z, xi2.w, xi3.x, xi3.y, xi3.z, xi3.w};
  float vj[16] = {xj0.x, xj0.y, xj0.z, xj0.w, xj1.x, xj1.y, xj1.z, xj1.w,
                  xj2.x, xj2.y, xj2.z, xj2.w, xj3.x, xj3.y, xj3.z, xj3.w};
#pragma unroll
  for (int f = 0; f < 16; ++f) {
    Aw[f * 66 + lane] = f2b(vi[f]);                 // x_i
    Aw[(16 + f) * 66 + lane] = f2b(vj[f] - vi[f]);  // x_j - x_i
  }
  __syncthreads();
  mlp_layer(Aw, Bw, wf + OFF_W0F, wf + OFF_B0F, 32, lane);
  __syncthreads();
  mlp_layer(Bw, Aw, wf + OFF_W1F, wf + OFF_B1F, 64, lane);
  __syncthreads();
  mlp_layer(Aw, Bw, wf + OFF_W2F, wf + OFF_B2F, 64, lane);
  atomicAdd(&cnt[dst], 1.0f);
  __syncthreads();
  // aggregation: one coalesced 64-lane atomic per edge (lane = feature)
  for (int eo = 0; eo < 64; ++eo) {
    int d = dsts[(w << 6) + eo];
    float vv = b2f(Bw[lane * 66 + eo]);
    atomicAdd(&y[d * 80 + lane], vv);
  }
}

__global__ __launch_bounds__(256) void node_kernel(
    float* __restrict__ y, const float* __restrict__ cnt, const float* __restrict__ x) {
  int idx = blockIdx.x * 256 + threadIdx.x;
  if (idx >= N_N * 80) return;
  int n = idx / 80;
  int j = idx - n * 80;
  float v;
  if (j < 64) v = y[idx] / fmaxf(cnt[n], 1.0f);
  else        v = x[n * 16 + (j - 64)];
  y[idx] = fmaxf(v, 0.f);
}

__global__ __launch_bounds__(256) void edge_out_kernel(
    const float* __restrict__ y, const int* __restrict__ ei,
    const float* __restrict__ we0t, const float* __restrict__ bee0,
    const float* __restrict__ we1, const float* __restrict__ bee1,
    float* __restrict__ out) {
  const int e = blockIdx.x * 256 + threadIdx.x;  // E_N % 256 == 0
  const int src = ei[e];
  const int dst = ei[E_N + e];
  const float4* ys = (const float4*)(y + (size_t)src * 80);
  const float4* yd = (const float4*)(y + (size_t)dst * 80);
  float d[80];
#pragma unroll
  for (int q = 0; q < 20; ++q) {
    float4 a = ys[q], b = yd[q];
    d[4 * q + 0] = a.x - b.x; d[4 * q + 1] = a.y - b.y;
    d[4 * q + 2] = a.z - b.z; d[4 * q + 3] = a.w - b.w;
  }
  float acc = bee1[0];
  for (int j = 0; j < 128; ++j) {
    const float4* w4 = (const float4*)(we0t + j * 80);
    float z0 = bee0[j], z1 = 0.f, z2 = 0.f, z3 = 0.f;
#pragma unroll
    for (int q = 0; q < 20; ++q) {
      float4 wv = w4[q];
      z0 = fmaf(d[4 * q + 0], wv.x, z0);
      z1 = fmaf(d[4 * q + 1], wv.y, z1);
      z2 = fmaf(d[4 * q + 2], wv.z, z2);
      z3 = fmaf(d[4 * q + 3], wv.w, z3);
    }
    float z = (z0 + z1) + (z2 + z3);
    acc = fmaf(fmaxf(z, 0.f), we1[j], acc);
  }
  out[e] = 1.0f / (1.0f + __expf(-acc));
}

extern "C" void kernel_launch(void* const* d_in, const int* in_sizes, int n_in,
                              void* d_out, int out_size, void* d_ws, size_t ws_size,
                              hipStream_t stream) {
  const float* x   = (const float*)d_in[0];
  const int* ei    = (const int*)d_in[1];
  const float* w0  = (const float*)d_in[2];
  const float* b0  = (const float*)d_in[3];
  const float* g0  = (const float*)d_in[4];
  const float* be0 = (const float*)d_in[5];
  const float* m0  = (const float*)d_in[6];
  const float* v0  = (const float*)d_in[7];
  const float* w1  = (const float*)d_in[8];
  const float* b1  = (const float*)d_in[9];
  const float* g1  = (const float*)d_in[10];
  const float* be1 = (const float*)d_in[11];
  const float* m1  = (const float*)d_in[12];
  const float* v1  = (const float*)d_in[13];
  const float* w2  = (const float*)d_in[14];
  const float* b2  = (const float*)d_in[15];
  const float* g2  = (const float*)d_in[16];
  const float* be2 = (const float*)d_in[17];
  const float* m2  = (const float*)d_in[18];
  const float* v2  = (const float*)d_in[19];
  const float* we0 = (const float*)d_in[20];
  const float* bee0= (const float*)d_in[21];
  const float* we1 = (const float*)d_in[22];
  const float* bee1= (const float*)d_in[23];
  float* out = (float*)d_out;
  float* ws  = (float*)d_ws;

  // zero agg accumulators + counts (ws is poisoned 0xAA before every launch)
  hipMemsetAsync(ws + OFF_Y, 0, (size_t)(N_N * 80 + N_N) * sizeof(float), stream);
  prep_kernel<<<1, 256, 0, stream>>>(w0, b0, g0, be0, m0, v0,
                                     w1, b1, g1, be1, m1, v1,
                                     w2, b2, g2, be2, m2, v2, we0, ws);
  edge_inner_kernel<<<E_N / 128, 128, 0, stream>>>(x, ei, ws, ws + OFF_Y, ws + OFF_CNT);
  node_kernel<<<(N_N * 80 + 255) / 256, 256, 0, stream>>>(ws + OFF_Y, ws + OFF_CNT, x);
  edge_out_kernel<<<E_N / 256, 256, 0, stream>>>(ws + OFF_Y, ei, ws + OFF_WE0T, bee0, we1, bee1, out);
}

// Round 2
// 1127.319 us; speedup vs baseline: 2.5004x; 2.5004x over previous
//
#include <hip/hip_runtime.h>

#define E_N 1600000
#define N_N 100000

// d_ws float-offset layout
#define OFF_WE0T 0        // 128*80 transposed end-layer0 weights
#define OFF_B0F  10240    // 64 fused biases (layer0)
#define OFF_B1F  10304
#define OFF_B2F  10368
#define OFF_FR0  10432    // layer0 weight A-frags: 2048 bf16 = 1024 floats
#define OFF_FR1  11456    // layer1: 4096 bf16 = 2048 floats
#define OFF_FR2  13504    // layer2: 4096 bf16 = 2048 floats
#define OFF_Y    15552    // N*80 (cols 0..63 agg accum, 64..79 relu(x))
#define OFF_CNT  8015552  // N
// total = 8,115,552 floats ≈ 32.5 MB

#define STR 72  // LDS activation row stride in bf16 (64 feats + 8 pad, keeps 16B align)

typedef __attribute__((ext_vector_type(8))) short bf16x8;
typedef __attribute__((ext_vector_type(4))) float f32x4;

static __device__ __forceinline__ float b2f(unsigned short u) {
  union { unsigned int i; float f; } c; c.i = ((unsigned int)u) << 16; return c.f;
}
static __device__ __forceinline__ unsigned short f2b(float f) {
  union { float f; unsigned int i; } c; c.f = f;
  unsigned int r = c.i + 0x7FFFu + ((c.i >> 16) & 1u);  // RNE
  return (unsigned short)(r >> 16);
}
static __device__ __forceinline__ unsigned int pack2(float a, float b) {
  return (unsigned int)f2b(a) | ((unsigned int)f2b(b) << 16);
}

__global__ void prep_kernel(
    const float* __restrict__ w0, const float* __restrict__ b0, const float* __restrict__ g0,
    const float* __restrict__ be0, const float* __restrict__ m0, const float* __restrict__ v0,
    const float* __restrict__ w1, const float* __restrict__ b1, const float* __restrict__ g1,
    const float* __restrict__ be1, const float* __restrict__ m1, const float* __restrict__ v1,
    const float* __restrict__ w2, const float* __restrict__ b2, const float* __restrict__ g2,
    const float* __restrict__ be2, const float* __restrict__ m2, const float* __restrict__ v2,
    const float* __restrict__ we0, float* __restrict__ ws) {
  __shared__ float s0[64], s1[64], s2[64];
  int t = threadIdx.x;
  if (t < 64) {
    s0[t] = g0[t] * rsqrtf(v0[t] + 1e-5f);
    s1[t] = g1[t] * rsqrtf(v1[t] + 1e-5f);
    s2[t] = g2[t] * rsqrtf(v2[t] + 1e-5f);
    ws[OFF_B0F + t] = (b0[t] - m0[t]) * s0[t] + be0[t];
    ws[OFF_B1F + t] = (b1[t] - m1[t]) * s1[t] + be1[t];
    ws[OFF_B2F + t] = (b2[t] - m2[t]) * s2[t] + be2[t];
  }
  __syncthreads();
  // weight A-fragments in exact MFMA lane order, bf16.
  // frag[i]: j=i&7, lane=(i>>3)&63, tile=i>>9 (tile = mt*KS+ks)
  // f = mt*16 + (lane&15); k = ks*32 + (lane>>4)*8 + j; val = w[k*64+f]*s[f]
  unsigned short* fr0 = (unsigned short*)(ws + OFF_FR0);
  unsigned short* fr1 = (unsigned short*)(ws + OFF_FR1);
  unsigned short* fr2 = (unsigned short*)(ws + OFF_FR2);
  for (int i = t; i < 2048; i += 256) {  // layer0: KS=1
    int j = i & 7, lane = (i >> 3) & 63, mt = i >> 9;
    int f = mt * 16 + (lane & 15);
    int k = (lane >> 4) * 8 + j;
    fr0[i] = f2b(w0[k * 64 + f] * s0[f]);
  }
  for (int i = t; i < 4096; i += 256) {  // layer1: KS=2
    int j = i & 7, lane = (i >> 3) & 63, tile = i >> 9;
    int mt = tile >> 1, ks = tile & 1;
    int f = mt * 16 + (lane & 15);
    int k = ks * 32 + (lane >> 4) * 8 + j;
    fr1[i] = f2b(w1[k * 64 + f] * s1[f]);
  }
  for (int i = t; i < 4096; i += 256) {  // layer2: KS=2
    int j = i & 7, lane = (i >> 3) & 63, tile = i >> 9;
    int mt = tile >> 1, ks = tile & 1;
    int f = mt * 16 + (lane & 15);
    int k = ks * 32 + (lane >> 4) * 8 + j;
    fr2[i] = f2b(w2[k * 64 + f] * s2[f]);
  }
  for (int i = t; i < 10240; i += 256) {
    int j = i / 80, k = i - j * 80;
    ws[OFF_WE0T + i] = we0[k * 128 + j];  // we0t[j][k] = we0[k][j]
  }
}

// One MFMA MLP layer over a wave's 64-edge tile.
// D[f][e] = sum_k W'[k][f] * act[e][k]; A = W'^T frags (global, precomputed),
// B = act from LDS [edge][feat]; C written back as [edge][feat] (b64 stores).
template <int KS>
static __device__ __forceinline__ void mfma_layer(
    unsigned short* A, const unsigned short* __restrict__ frag,
    const float* __restrict__ bias, int lane) {
  const int m = lane & 15;
  const int quad = lane >> 4;
  bf16x8 wf[4][KS];
#pragma unroll
  for (int mt = 0; mt < 4; ++mt)
#pragma unroll
    for (int ks = 0; ks < KS; ++ks)
      wf[mt][ks] = *(const bf16x8*)(frag + (((mt * KS + ks) * 64) + lane) * 8);
  f32x4 binit[4];
#pragma unroll
  for (int mt = 0; mt < 4; ++mt)
    binit[mt] = *(const f32x4*)(bias + mt * 16 + quad * 4);
  f32x4 acc[4][4];
#pragma unroll
  for (int mt = 0; mt < 4; ++mt)
#pragma unroll
    for (int nt = 0; nt < 4; ++nt) acc[mt][nt] = binit[mt];
#pragma unroll
  for (int nt = 0; nt < 4; ++nt) {
#pragma unroll
    for (int ks = 0; ks < KS; ++ks) {
      bf16x8 bfr = *(const bf16x8*)(A + (nt * 16 + m) * STR + ks * 32 + quad * 8);
#pragma unroll
      for (int mt = 0; mt < 4; ++mt)
        acc[mt][nt] = __builtin_amdgcn_mfma_f32_16x16x32_bf16(wf[mt][ks], bfr, acc[mt][nt], 0, 0, 0);
    }
  }
  __syncthreads();  // all B-frag reads done before overwriting the tile
#pragma unroll
  for (int mt = 0; mt < 4; ++mt) {
#pragma unroll
    for (int nt = 0; nt < 4; ++nt) {
      f32x4 a = acc[mt][nt];
      uint2 p;
      p.x = pack2(fmaxf(a.x, 0.f), fmaxf(a.y, 0.f));
      p.y = pack2(fmaxf(a.z, 0.f), fmaxf(a.w, 0.f));
      *(uint2*)(A + (nt * 16 + m) * STR + mt * 16 + quad * 4) = p;
    }
  }
  __syncthreads();
}

__global__ __launch_bounds__(256) void edge_inner_kernel(
    const float* __restrict__ x, const int* __restrict__ ei,
    const float* __restrict__ ws, float* __restrict__ y, float* __restrict__ cnt) {
  __shared__ unsigned short act[4][64 * STR];
  __shared__ int dsts[256];
  const int tid = threadIdx.x;
  const int w = tid >> 6;
  const int lane = tid & 63;
  unsigned short* A = act[w];

  const int e = blockIdx.x * 256 + tid;  // E_N % 256 == 0
  const int src = ei[e];
  const int dst = ei[E_N + e];
  dsts[tid] = dst;

  const float4* x4 = (const float4*)x;
  float4 xi0 = x4[dst * 4 + 0], xi1 = x4[dst * 4 + 1], xi2 = x4[dst * 4 + 2], xi3 = x4[dst * 4 + 3];
  float4 xj0 = x4[src * 4 + 0], xj1 = x4[src * 4 + 1], xj2 = x4[src * 4 + 2], xj3 = x4[src * 4 + 3];
  float vi[16] = {xi0.x, xi0.y, xi0.z, xi0.w, xi1.x, xi1.y, xi1.z, xi1.w,
                  xi2.x, xi2.y, xi2.z, xi2.w, xi3.x, xi3.y, xi3.z, xi3.w};
  float vj[16] = {xj0.x, xj0.y, xj0.z, xj0.w, xj1.x, xj1.y, xj1.z, xj1.w,
                  xj2.x, xj2.y, xj2.z, xj2.w, xj3.x, xj3.y, xj3.z, xj3.w};
  unsigned int* row = (unsigned int*)(A + lane * STR);
#pragma unroll
  for (int q = 0; q < 8; ++q) row[q] = pack2(vi[2 * q], vi[2 * q + 1]);            // x_i -> feats 0..15
#pragma unroll
  for (int q = 0; q < 8; ++q)                                                       // x_j - x_i -> 16..31
    row[8 + q] = pack2(vj[2 * q] - vi[2 * q], vj[2 * q + 1] - vi[2 * q + 1]);
  __syncthreads();

  const unsigned short* fr0 = (const unsigned short*)(ws + OFF_FR0);
  const unsigned short* fr1 = (const unsigned short*)(ws + OFF_FR1);
  const unsigned short* fr2 = (const unsigned short*)(ws + OFF_FR2);
  mfma_layer<1>(A, fr0, ws + OFF_B0F, lane);
  mfma_layer<2>(A, fr1, ws + OFF_B1F, lane);
  mfma_layer<2>(A, fr2, ws + OFF_B2F, lane);

  atomicAdd(&cnt[dst], 1.0f);
  // aggregation: lane = feature, loop edges -> one coalesced 64-lane atomic per edge
  for (int eo = 0; eo < 64; ++eo) {
    int d = dsts[(w << 6) + eo];
    float vv = b2f(A[eo * STR + lane]);
    atomicAdd(&y[d * 80 + lane], vv);
  }
}

__global__ __launch_bounds__(256) void node_kernel(
    float* __restrict__ y, const float* __restrict__ cnt, const float* __restrict__ x) {
  int idx = blockIdx.x * 256 + threadIdx.x;
  if (idx >= N_N * 80) return;
  int n = idx / 80;
  int j = idx - n * 80;
  float v;
  if (j < 64) v = y[idx] / fmaxf(cnt[n], 1.0f);
  else        v = x[n * 16 + (j - 64)];
  y[idx] = fmaxf(v, 0.f);
}

__global__ __launch_bounds__(256) void edge_out_kernel(
    const float* __restrict__ y, const int* __restrict__ ei,
    const float* __restrict__ we0t, const float* __restrict__ bee0,
    const float* __restrict__ we1, const float* __restrict__ bee1,
    float* __restrict__ out) {
  const int e = blockIdx.x * 256 + threadIdx.x;  // E_N % 256 == 0
  const int src = ei[e];
  const int dst = ei[E_N + e];
  const float4* ys = (const float4*)(y + (size_t)src * 80);
  const float4* yd = (const float4*)(y + (size_t)dst * 80);
  float d[80];
#pragma unroll
  for (int q = 0; q < 20; ++q) {
    float4 a = ys[q], b = yd[q];
    d[4 * q + 0] = a.x - b.x; d[4 * q + 1] = a.y - b.y;
    d[4 * q + 2] = a.z - b.z; d[4 * q + 3] = a.w - b.w;
  }
  float acc = bee1[0];
  for (int j = 0; j < 128; ++j) {
    const float4* w4 = (const float4*)(we0t + j * 80);
    float z0 = bee0[j], z1 = 0.f, z2 = 0.f, z3 = 0.f;
#pragma unroll
    for (int q = 0; q < 20; ++q) {
      float4 wv = w4[q];
      z0 = fmaf(d[4 * q + 0], wv.x, z0);
      z1 = fmaf(d[4 * q + 1], wv.y, z1);
      z2 = fmaf(d[4 * q + 2], wv.z, z2);
      z3 = fmaf(d[4 * q + 3], wv.w, z3);
    }
    float z = (z0 + z1) + (z2 + z3);
    acc = fmaf(fmaxf(z, 0.f), we1[j], acc);
  }
  out[e] = 1.0f / (1.0f + __expf(-acc));
}

extern "C" void kernel_launch(void* const* d_in, const int* in_sizes, int n_in,
                              void* d_out, int out_size, void* d_ws, size_t ws_size,
                              hipStream_t stream) {
  const float* x   = (const float*)d_in[0];
  const int* ei    = (const int*)d_in[1];
  const float* w0  = (const float*)d_in[2];
  const float* b0  = (const float*)d_in[3];
  const float* g0  = (const float*)d_in[4];
  const float* be0 = (const float*)d_in[5];
  const float* m0  = (const float*)d_in[6];
  const float* v0  = (const float*)d_in[7];
  const float* w1  = (const float*)d_in[8];
  const float* b1  = (const float*)d_in[9];
  const float* g1  = (const float*)d_in[10];
  const float* be1 = (const float*)d_in[11];
  const float* m1  = (const float*)d_in[12];
  const float* v1  = (const float*)d_in[13];
  const float* w2  = (const float*)d_in[14];
  const float* b2  = (const float*)d_in[15];
  const float* g2  = (const float*)d_in[16];
  const float* be2 = (const float*)d_in[17];
  const float* m2  = (const float*)d_in[18];
  const float* v2  = (const float*)d_in[19];
  const float* we0 = (const float*)d_in[20];
  const float* bee0= (const float*)d_in[21];
  const float* we1 = (const float*)d_in[22];
  const float* bee1= (const float*)d_in[23];
  float* out = (float*)d_out;
  float* ws  = (float*)d_ws;

  hipMemsetAsync(ws + OFF_Y, 0, (size_t)(N_N * 80 + N_N) * sizeof(float), stream);
  prep_kernel<<<1, 256, 0, stream>>>(w0, b0, g0, be0, m0, v0,
                                     w1, b1, g1, be1, m1, v1,
                                     w2, b2, g2, be2, m2, v2, we0, ws);
  edge_inner_kernel<<<E_N / 256, 256, 0, stream>>>(x, ei, ws, ws + OFF_Y, ws + OFF_CNT);
  node_kernel<<<(N_N * 80 + 255) / 256, 256, 0, stream>>>(ws + OFF_Y, ws + OFF_CNT, x);
  edge_out_kernel<<<E_N / 256, 256, 0, stream>>>(ws + OFF_Y, ei, ws + OFF_WE0T, bee0, we1, bee1, out);
}

// Round 4
// 693.311 us; speedup vs baseline: 4.0656x; 1.6260x over previous
//
#include <hip/hip_runtime.h>

#define E_N 1600000
#define N_N 100000

// d_ws float-offset layout
#define OFF_B0F  0        // 64 fused biases (inner layer0)
#define OFF_B1F  64
#define OFF_B2F  128
#define OFF_FR0  192      // inner layer0 weight A-frags: 2048 bf16 = 1024 floats
#define OFF_FR1  1216     // layer1: 4096 bf16
#define OFF_FR2  3264     // layer2: 4096 bf16
#define OFF_FE0  5312     // end-layer0 A-frags: 12288 bf16 = 6144 floats (K padded 80->96)
#define OFF_YBF  11456    // N*80 bf16 = 4,000,000 floats
#define OFF_YACC 4011456  // N*64 fp32 aggregation accumulator
#define OFF_CNT  10411456 // N
// total = 10,511,456 floats ≈ 42.0 MB

#define STR 72   // inner LDS activation row stride (bf16)
#define OSTR 104 // edge_out LDS diff row stride (bf16): 96 used + 8 pad, 16B-aligned rows

typedef __attribute__((ext_vector_type(8))) short bf16x8;
typedef __attribute__((ext_vector_type(4))) float f32x4;

static __device__ __forceinline__ float b2f(unsigned short u) {
  union { unsigned int i; float f; } c; c.i = ((unsigned int)u) << 16; return c.f;
}
static __device__ __forceinline__ unsigned short f2b(float f) {
  union { float f; unsigned int i; } c; c.f = f;
  unsigned int r = c.i + 0x7FFFu + ((c.i >> 16) & 1u);  // RNE
  return (unsigned short)(r >> 16);
}
static __device__ __forceinline__ unsigned int pack2(float a, float b) {
  return (unsigned int)f2b(a) | ((unsigned int)f2b(b) << 16);
}

__global__ void prep_kernel(
    const float* __restrict__ w0, const float* __restrict__ b0, const float* __restrict__ g0,
    const float* __restrict__ be0, const float* __restrict__ m0, const float* __restrict__ v0,
    const float* __restrict__ w1, const float* __restrict__ b1, const float* __restrict__ g1,
    const float* __restrict__ be1, const float* __restrict__ m1, const float* __restrict__ v1,
    const float* __restrict__ w2, const float* __restrict__ b2, const float* __restrict__ g2,
    const float* __restrict__ be2, const float* __restrict__ m2, const float* __restrict__ v2,
    const float* __restrict__ we0, float* __restrict__ ws) {
  __shared__ float s0[64], s1[64], s2[64];
  int t = threadIdx.x;
  if (t < 64) {
    s0[t] = g0[t] * rsqrtf(v0[t] + 1e-5f);
    s1[t] = g1[t] * rsqrtf(v1[t] + 1e-5f);
    s2[t] = g2[t] * rsqrtf(v2[t] + 1e-5f);
    ws[OFF_B0F + t] = (b0[t] - m0[t]) * s0[t] + be0[t];
    ws[OFF_B1F + t] = (b1[t] - m1[t]) * s1[t] + be1[t];
    ws[OFF_B2F + t] = (b2[t] - m2[t]) * s2[t] + be2[t];
  }
  __syncthreads();
  // weight A-frags in MFMA lane order: f = mt*16+(lane&15), k = ks*32+(lane>>4)*8+j
  unsigned short* fr0 = (unsigned short*)(ws + OFF_FR0);
  unsigned short* fr1 = (unsigned short*)(ws + OFF_FR1);
  unsigned short* fr2 = (unsigned short*)(ws + OFF_FR2);
  for (int i = t; i < 2048; i += 256) {  // layer0: KS=1
    int j = i & 7, lane = (i >> 3) & 63, mt = i >> 9;
    int f = mt * 16 + (lane & 15);
    int k = (lane >> 4) * 8 + j;
    fr0[i] = f2b(w0[k * 64 + f] * s0[f]);
  }
  for (int i = t; i < 4096; i += 256) {  // layer1: KS=2
    int j = i & 7, lane = (i >> 3) & 63, tile = i >> 9;
    int mt = tile >> 1, ks = tile & 1;
    int f = mt * 16 + (lane & 15);
    int k = ks * 32 + (lane >> 4) * 8 + j;
    fr1[i] = f2b(w1[k * 64 + f] * s1[f]);
  }
  for (int i = t; i < 4096; i += 256) {  // layer2: KS=2
    int j = i & 7, lane = (i >> 3) & 63, tile = i >> 9;
    int mt = tile >> 1, ks = tile & 1;
    int f = mt * 16 + (lane & 15);
    int k = ks * 32 + (lane >> 4) * 8 + j;
    fr2[i] = f2b(w2[k * 64 + f] * s2[f]);
  }
  // end-layer0 A-frags: h = mt*16+(lane&15), k = ks*32+(lane>>4)*8+j, zero for k>=80
  unsigned short* fe0 = (unsigned short*)(ws + OFF_FE0);
  for (int i = t; i < 12288; i += 256) {
    int j = i & 7, lane = (i >> 3) & 63, tile = i >> 9;  // tile = mt*3+ks, 0..23
    int mt = tile / 3, ks = tile - mt * 3;
    int h = mt * 16 + (lane & 15);
    int k = ks * 32 + ((lane >> 4) & 3) * 8 + j;
    fe0[i] = (k < 80) ? f2b(we0[k * 128 + h]) : (unsigned short)0;
  }
}

// inner MFMA MLP layer over a wave's 64-edge tile (layout verified in R2)
template <int KS>
static __device__ __forceinline__ void mfma_layer(
    unsigned short* A, const unsigned short* __restrict__ frag,
    const float* __restrict__ bias, int lane) {
  const int m = lane & 15;
  const int quad = lane >> 4;
  bf16x8 wf[4][KS];
#pragma unroll
  for (int mt = 0; mt < 4; ++mt)
#pragma unroll
    for (int ks = 0; ks < KS; ++ks)
      wf[mt][ks] = *(const bf16x8*)(frag + (((mt * KS + ks) * 64) + lane) * 8);
  f32x4 binit[4];
#pragma unroll
  for (int mt = 0; mt < 4; ++mt)
    binit[mt] = *(const f32x4*)(bias + mt * 16 + quad * 4);
  f32x4 acc[4][4];
#pragma unroll
  for (int mt = 0; mt < 4; ++mt)
#pragma unroll
    for (int nt = 0; nt < 4; ++nt) acc[mt][nt] = binit[mt];
#pragma unroll
  for (int nt = 0; nt < 4; ++nt) {
#pragma unroll
    for (int ks = 0; ks < KS; ++ks) {
      bf16x8 bfr = *(const bf16x8*)(A + (nt * 16 + m) * STR + ks * 32 + quad * 8);
#pragma unroll
      for (int mt = 0; mt < 4; ++mt)
        acc[mt][nt] = __builtin_amdgcn_mfma_f32_16x16x32_bf16(wf[mt][ks], bfr, acc[mt][nt], 0, 0, 0);
    }
  }
  __syncthreads();
#pragma unroll
  for (int mt = 0; mt < 4; ++mt) {
#pragma unroll
    for (int nt = 0; nt < 4; ++nt) {
      f32x4 a = acc[mt][nt];
      uint2 p;
      p.x = pack2(fmaxf(a.x, 0.f), fmaxf(a.y, 0.f));
      p.y = pack2(fmaxf(a.z, 0.f), fmaxf(a.w, 0.f));
      *(uint2*)(A + (nt * 16 + m) * STR + mt * 16 + quad * 4) = p;
    }
  }
  __syncthreads();
}

__global__ __launch_bounds__(256) void edge_inner_kernel(
    const float* __restrict__ x, const int* __restrict__ ei,
    const float* __restrict__ ws, float* __restrict__ yacc, float* __restrict__ cnt) {
  __shared__ unsigned short act[4][64 * STR];
  __shared__ int dsts[256];
  const int tid = threadIdx.x;
  const int w = tid >> 6;
  const int lane = tid & 63;
  unsigned short* A = act[w];

  const int e = blockIdx.x * 256 + tid;  // E_N % 256 == 0
  const int src = ei[e];
  const int dst = ei[E_N + e];
  dsts[tid] = dst;

  const float4* x4 = (const float4*)x;
  float4 xi0 = x4[dst * 4 + 0], xi1 = x4[dst * 4 + 1], xi2 = x4[dst * 4 + 2], xi3 = x4[dst * 4 + 3];
  float4 xj0 = x4[src * 4 + 0], xj1 = x4[src * 4 + 1], xj2 = x4[src * 4 + 2], xj3 = x4[src * 4 + 3];
  float vi[16] = {xi0.x, xi0.y, xi0.z, xi0.w, xi1.x, xi1.y, xi1.z, xi1.w,
                  xi2.x, xi2.y, xi2.z, xi2.w, xi3.x, xi3.y, xi3.z, xi3.w};
  float vj[16] = {xj0.x, xj0.y, xj0.z, xj0.w, xj1.x, xj1.y, xj1.z, xj1.w,
                  xj2.x, xj2.y, xj2.z, xj2.w, xj3.x, xj3.y, xj3.z, xj3.w};
  unsigned int* row = (unsigned int*)(A + lane * STR);
#pragma unroll
  for (int q = 0; q < 8; ++q) row[q] = pack2(vi[2 * q], vi[2 * q + 1]);
#pragma unroll
  for (int q = 0; q < 8; ++q)
    row[8 + q] = pack2(vj[2 * q] - vi[2 * q], vj[2 * q + 1] - vi[2 * q + 1]);
  __syncthreads();

  const unsigned short* fr0 = (const unsigned short*)(ws + OFF_FR0);
  const unsigned short* fr1 = (const unsigned short*)(ws + OFF_FR1);
  const unsigned short* fr2 = (const unsigned short*)(ws + OFF_FR2);
  mfma_layer<1>(A, fr0, ws + OFF_B0F, lane);
  mfma_layer<2>(A, fr1, ws + OFF_B1F, lane);
  mfma_layer<2>(A, fr2, ws + OFF_B2F, lane);

  atomicAdd(&cnt[dst], 1.0f);
  // lane = feature; one dense coalesced 64-lane (256 B) atomic row per edge
  for (int eo = 0; eo < 64; ++eo) {
    int d = dsts[(w << 6) + eo];
    float vv = b2f(A[eo * STR + lane]);
    atomicAdd(&yacc[d * 64 + lane], vv);
  }
}

__global__ __launch_bounds__(256) void node_kernel(
    const float* __restrict__ yacc, const float* __restrict__ cnt,
    const float* __restrict__ x, unsigned short* __restrict__ ybf) {
  int idx = blockIdx.x * 256 + threadIdx.x;
  if (idx >= N_N * 80) return;
  int n = idx / 80;
  int j = idx - n * 80;
  float v;
  if (j < 64) v = yacc[n * 64 + j] / fmaxf(cnt[n], 1.0f);
  else        v = x[n * 16 + (j - 64)];
  ybf[idx] = f2b(fmaxf(v, 0.f));
}

// MFMA end-MLP: D[h=128][e=64] per wave, K=80 padded to 96; epilogue fuses relu + we1 dot + sigmoid
__global__ __launch_bounds__(256) void edge_out_kernel(
    const unsigned short* __restrict__ ybf, const int* __restrict__ ei,
    const unsigned short* __restrict__ fe0, const float* __restrict__ bee0,
    const float* __restrict__ we1, const float* __restrict__ bee1,
    float* __restrict__ out) {
  __shared__ unsigned short Dt[4][64 * OSTR];  // 53,248 B
  const int tid = threadIdx.x, w = tid >> 6, lane = tid & 63;
  const int quad = lane >> 4, m = lane & 15;
  unsigned short* Dw = Dt[w];
  const int e = blockIdx.x * 256 + tid;
  const int src = ei[e], dst = ei[E_N + e];
  const bf16x8* ps = (const bf16x8*)(ybf + (size_t)src * 80);
  const bf16x8* pd = (const bf16x8*)(ybf + (size_t)dst * 80);
  uint4* drow = (uint4*)(Dw + lane * OSTR);
  // 80 feats = 10 bf16x8 loads (R3 bug: was 5 -> half the row was garbage)
#pragma unroll
  for (int q = 0; q < 10; ++q) {
    bf16x8 a = ps[q], b = pd[q];
    uint4 p;
    p.x = pack2(b2f((unsigned short)a[0]) - b2f((unsigned short)b[0]),
                b2f((unsigned short)a[1]) - b2f((unsigned short)b[1]));
    p.y = pack2(b2f((unsigned short)a[2]) - b2f((unsigned short)b[2]),
                b2f((unsigned short)a[3]) - b2f((unsigned short)b[3]));
    p.z = pack2(b2f((unsigned short)a[4]) - b2f((unsigned short)b[4]),
                b2f((unsigned short)a[5]) - b2f((unsigned short)b[5]));
    p.w = pack2(b2f((unsigned short)a[6]) - b2f((unsigned short)b[6]),
                b2f((unsigned short)a[7]) - b2f((unsigned short)b[7]));
    drow[q] = p;
  }
  { uint4 z; z.x = z.y = z.z = z.w = 0u; drow[10] = z; drow[11] = z; }  // pad k=80..95
  __syncthreads();

  // cache B-frags (12 ds_read_b128)
  bf16x8 bf[4][3];
#pragma unroll
  for (int nt = 0; nt < 4; ++nt)
#pragma unroll
    for (int ks = 0; ks < 3; ++ks)
      bf[nt][ks] = *(const bf16x8*)(Dw + (nt * 16 + m) * OSTR + ks * 32 + quad * 8);

  float fin[4] = {0.f, 0.f, 0.f, 0.f};
  for (int mt = 0; mt < 8; ++mt) {
    bf16x8 wf[3];
#pragma unroll
    for (int ks = 0; ks < 3; ++ks)
      wf[ks] = *(const bf16x8*)(fe0 + (size_t)(((mt * 3 + ks) * 64) + lane) * 8);
    f32x4 binit = *(const f32x4*)(bee0 + mt * 16 + quad * 4);
    float4 w1v = *(const float4*)(we1 + mt * 16 + quad * 4);
    f32x4 acc[4];
#pragma unroll
    for (int nt = 0; nt < 4; ++nt) acc[nt] = binit;
#pragma unroll
    for (int nt = 0; nt < 4; ++nt)
#pragma unroll
      for (int ks = 0; ks < 3; ++ks)
        acc[nt] = __builtin_amdgcn_mfma_f32_16x16x32_bf16(wf[ks], bf[nt][ks], acc[nt], 0, 0, 0);
#pragma unroll
    for (int nt = 0; nt < 4; ++nt) {
      f32x4 a = acc[nt];
      fin[nt] += fmaxf(a.x, 0.f) * w1v.x + fmaxf(a.y, 0.f) * w1v.y +
                 fmaxf(a.z, 0.f) * w1v.z + fmaxf(a.w, 0.f) * w1v.w;
    }
  }
  // cross-quad reduction: lanes {c,16+c,32+c,48+c} hold partials of col c
#pragma unroll
  for (int nt = 0; nt < 4; ++nt) {
    float v = fin[nt];
    v += __shfl_xor(v, 16);
    v += __shfl_xor(v, 32);
    fin[nt] = v;
  }
  float z = (quad == 0) ? fin[0] : (quad == 1) ? fin[1] : (quad == 2) ? fin[2] : fin[3];
  z += bee1[0];
  out[e] = 1.0f / (1.0f + __expf(-z));
}

extern "C" void kernel_launch(void* const* d_in, const int* in_sizes, int n_in,
                              void* d_out, int out_size, void* d_ws, size_t ws_size,
                              hipStream_t stream) {
  const float* x   = (const float*)d_in[0];
  const int* ei    = (const int*)d_in[1];
  const float* w0  = (const float*)d_in[2];
  const float* b0  = (const float*)d_in[3];
  const float* g0  = (const float*)d_in[4];
  const float* be0 = (const float*)d_in[5];
  const float* m0  = (const float*)d_in[6];
  const float* v0  = (const float*)d_in[7];
  const float* w1  = (const float*)d_in[8];
  const float* b1  = (const float*)d_in[9];
  const float* g1  = (const float*)d_in[10];
  const float* be1 = (const float*)d_in[11];
  const float* m1  = (const float*)d_in[12];
  const float* v1  = (const float*)d_in[13];
  const float* w2  = (const float*)d_in[14];
  const float* b2  = (const float*)d_in[15];
  const float* g2  = (const float*)d_in[16];
  const float* be2 = (const float*)d_in[17];
  const float* m2  = (const float*)d_in[18];
  const float* v2  = (const float*)d_in[19];
  const float* we0 = (const float*)d_in[20];
  const float* bee0= (const float*)d_in[21];
  const float* we1 = (const float*)d_in[22];
  const float* bee1= (const float*)d_in[23];
  float* out = (float*)d_out;
  float* ws  = (float*)d_ws;

  hipMemsetAsync(ws + OFF_YACC, 0, (size_t)(N_N * 64 + N_N) * sizeof(float), stream);
  prep_kernel<<<1, 256, 0, stream>>>(w0, b0, g0, be0, m0, v0,
                                     w1, b1, g1, be1, m1, v1,
                                     w2, b2, g2, be2, m2, v2, we0, ws);
  edge_inner_kernel<<<E_N / 256, 256, 0, stream>>>(x, ei, ws, ws + OFF_YACC, ws + OFF_CNT);
  node_kernel<<<(N_N * 80 + 255) / 256, 256, 0, stream>>>(ws + OFF_YACC, ws + OFF_CNT, x,
                                                          (unsigned short*)(ws + OFF_YBF));
  edge_out_kernel<<<E_N / 256, 256, 0, stream>>>((const unsigned short*)(ws + OFF_YBF), ei,
                                                 (const unsigned short*)(ws + OFF_FE0),
                                                 bee0, we1, bee1, out);
}

// Round 5
// 526.531 us; speedup vs baseline: 5.3534x; 1.3168x over previous
//
#include <hip/hip_runtime.h>

#define E_N 1600000
#define N_N 100000
#define SCAN_B 98  // ceil(N_N/1024)

// d_ws float-offset layout
#define OFF_B0F  0
#define OFF_B1F  64
#define OFF_B2F  128
#define OFF_FR0  192       // inner layer0 A-frags: 2048 bf16
#define OFF_FR1  1216      // 4096 bf16
#define OFF_FR2  3264      // 4096 bf16
#define OFF_FE0  5312      // end-layer0 A-frags: 12288 bf16
#define OFF_YBF  11456     // N*80 bf16
#define OFF_YACC 4011456   // N*64 fp32 agg accumulator; zperm (E floats) aliases it after node_kernel
#define OFF_CNT  10411456  // N ints (in-degree histogram)
#define OFF_CUR  10511456  // 100352 ints (exclusive offsets -> scatter cursor)
#define OFF_BSUM 10611808  // 128 ints
#define OFF_SRCS 10611936  // E ints (src, dst-sorted order)
#define OFF_DSTS 12211936  // E ints (dst, sorted ascending)
#define OFF_IPOS 13811936  // E ints (e -> sorted position)
// total = 15,411,936 floats ≈ 61.6 MB

#define STR 72   // inner LDS activation row stride (bf16)
#define OSTR 104 // edge_out LDS diff row stride (bf16)

typedef __attribute__((ext_vector_type(8))) short bf16x8;
typedef __attribute__((ext_vector_type(4))) float f32x4;

static __device__ __forceinline__ float b2f(unsigned short u) {
  union { unsigned int i; float f; } c; c.i = ((unsigned int)u) << 16; return c.f;
}
static __device__ __forceinline__ unsigned short f2b(float f) {
  union { float f; unsigned int i; } c; c.f = f;
  unsigned int r = c.i + 0x7FFFu + ((c.i >> 16) & 1u);  // RNE
  return (unsigned short)(r >> 16);
}
static __device__ __forceinline__ unsigned int pack2(float a, float b) {
  return (unsigned int)f2b(a) | ((unsigned int)f2b(b) << 16);
}

__global__ void prep_kernel(
    const float* __restrict__ w0, const float* __restrict__ b0, const float* __restrict__ g0,
    const float* __restrict__ be0, const float* __restrict__ m0, const float* __restrict__ v0,
    const float* __restrict__ w1, const float* __restrict__ b1, const float* __restrict__ g1,
    const float* __restrict__ be1, const float* __restrict__ m1, const float* __restrict__ v1,
    const float* __restrict__ w2, const float* __restrict__ b2, const float* __restrict__ g2,
    const float* __restrict__ be2, const float* __restrict__ m2, const float* __restrict__ v2,
    const float* __restrict__ we0, float* __restrict__ ws) {
  __shared__ float s0[64], s1[64], s2[64];
  int t = threadIdx.x;
  if (t < 64) {
    s0[t] = g0[t] * rsqrtf(v0[t] + 1e-5f);
    s1[t] = g1[t] * rsqrtf(v1[t] + 1e-5f);
    s2[t] = g2[t] * rsqrtf(v2[t] + 1e-5f);
    ws[OFF_B0F + t] = (b0[t] - m0[t]) * s0[t] + be0[t];
    ws[OFF_B1F + t] = (b1[t] - m1[t]) * s1[t] + be1[t];
    ws[OFF_B2F + t] = (b2[t] - m2[t]) * s2[t] + be2[t];
  }
  __syncthreads();
  unsigned short* fr0 = (unsigned short*)(ws + OFF_FR0);
  unsigned short* fr1 = (unsigned short*)(ws + OFF_FR1);
  unsigned short* fr2 = (unsigned short*)(ws + OFF_FR2);
  for (int i = t; i < 2048; i += 256) {  // layer0: KS=1
    int j = i & 7, lane = (i >> 3) & 63, mt = i >> 9;
    int f = mt * 16 + (lane & 15);
    int k = (lane >> 4) * 8 + j;
    fr0[i] = f2b(w0[k * 64 + f] * s0[f]);
  }
  for (int i = t; i < 4096; i += 256) {  // layer1: KS=2
    int j = i & 7, lane = (i >> 3) & 63, tile = i >> 9;
    int mt = tile >> 1, ks = tile & 1;
    int f = mt * 16 + (lane & 15);
    int k = ks * 32 + (lane >> 4) * 8 + j;
    fr1[i] = f2b(w1[k * 64 + f] * s1[f]);
  }
  for (int i = t; i < 4096; i += 256) {  // layer2: KS=2
    int j = i & 7, lane = (i >> 3) & 63, tile = i >> 9;
    int mt = tile >> 1, ks = tile & 1;
    int f = mt * 16 + (lane & 15);
    int k = ks * 32 + (lane >> 4) * 8 + j;
    fr2[i] = f2b(w2[k * 64 + f] * s2[f]);
  }
  unsigned short* fe0 = (unsigned short*)(ws + OFF_FE0);
  for (int i = t; i < 12288; i += 256) {
    int j = i & 7, lane = (i >> 3) & 63, tile = i >> 9;  // tile = mt*3+ks
    int mt = tile / 3, ks = tile - mt * 3;
    int h = mt * 16 + (lane & 15);
    int k = ks * 32 + ((lane >> 4) & 3) * 8 + j;
    fe0[i] = (k < 80) ? f2b(we0[k * 128 + h]) : (unsigned short)0;
  }
}

// ---------- dst-sort pipeline ----------
__global__ __launch_bounds__(256) void hist_kernel(const int* __restrict__ ei,
                                                   int* __restrict__ counts) {
  int e = blockIdx.x * 256 + threadIdx.x;
  if (e < E_N) atomicAdd(&counts[ei[E_N + e]], 1);
}

__global__ __launch_bounds__(1024) void scan1_kernel(const int* __restrict__ counts,
                                                     int* __restrict__ cursor,
                                                     int* __restrict__ bsum) {
  __shared__ int s[1024];
  int t = threadIdx.x;
  int i = blockIdx.x * 1024 + t;
  int v = (i < N_N) ? counts[i] : 0;
  s[t] = v;
  __syncthreads();
  for (int off = 1; off < 1024; off <<= 1) {
    int a = (t >= off) ? s[t - off] : 0;
    __syncthreads();
    s[t] += a;
    __syncthreads();
  }
  cursor[i] = s[t] - v;  // block-local exclusive
  if (t == 1023) bsum[blockIdx.x] = s[1023];
}

__global__ __launch_bounds__(128) void scan2_kernel(int* __restrict__ bsum) {
  __shared__ int s[128];
  int t = threadIdx.x;
  int v = (t < SCAN_B) ? bsum[t] : 0;
  s[t] = v;
  __syncthreads();
  for (int off = 1; off < 128; off <<= 1) {
    int a = (t >= off) ? s[t - off] : 0;
    __syncthreads();
    s[t] += a;
    __syncthreads();
  }
  if (t < SCAN_B) bsum[t] = s[t] - v;  // exclusive block bases
}

__global__ __launch_bounds__(1024) void scan3_kernel(int* __restrict__ cursor,
                                                     const int* __restrict__ bsum) {
  int i = blockIdx.x * 1024 + threadIdx.x;
  cursor[i] += bsum[blockIdx.x];
}

__global__ __launch_bounds__(256) void scatter_kernel(const int* __restrict__ ei,
                                                      int* __restrict__ cursor,
                                                      int* __restrict__ srcs,
                                                      int* __restrict__ dsts,
                                                      int* __restrict__ ipos) {
  int e = blockIdx.x * 256 + threadIdx.x;
  if (e >= E_N) return;
  int s = ei[e], d = ei[E_N + e];
  int pos = atomicAdd(&cursor[d], 1);
  srcs[pos] = s;
  dsts[pos] = d;
  ipos[e] = pos;
}

// ---------- inner MLP (MFMA), edges in dst-sorted order ----------
template <int KS>
static __device__ __forceinline__ void mfma_layer(
    unsigned short* A, const unsigned short* __restrict__ frag,
    const float* __restrict__ bias, int lane) {
  const int m = lane & 15;
  const int quad = lane >> 4;
  bf16x8 wf[4][KS];
#pragma unroll
  for (int mt = 0; mt < 4; ++mt)
#pragma unroll
    for (int ks = 0; ks < KS; ++ks)
      wf[mt][ks] = *(const bf16x8*)(frag + (((mt * KS + ks) * 64) + lane) * 8);
  f32x4 binit[4];
#pragma unroll
  for (int mt = 0; mt < 4; ++mt)
    binit[mt] = *(const f32x4*)(bias + mt * 16 + quad * 4);
  f32x4 acc[4][4];
#pragma unroll
  for (int mt = 0; mt < 4; ++mt)
#pragma unroll
    for (int nt = 0; nt < 4; ++nt) acc[mt][nt] = binit[mt];
#pragma unroll
  for (int nt = 0; nt < 4; ++nt) {
#pragma unroll
    for (int ks = 0; ks < KS; ++ks) {
      bf16x8 bfr = *(const bf16x8*)(A + (nt * 16 + m) * STR + ks * 32 + quad * 8);
#pragma unroll
      for (int mt = 0; mt < 4; ++mt)
        acc[mt][nt] = __builtin_amdgcn_mfma_f32_16x16x32_bf16(wf[mt][ks], bfr, acc[mt][nt], 0, 0, 0);
    }
  }
  __syncthreads();
#pragma unroll
  for (int mt = 0; mt < 4; ++mt) {
#pragma unroll
    for (int nt = 0; nt < 4; ++nt) {
      f32x4 a = acc[mt][nt];
      uint2 p;
      p.x = pack2(fmaxf(a.x, 0.f), fmaxf(a.y, 0.f));
      p.y = pack2(fmaxf(a.z, 0.f), fmaxf(a.w, 0.f));
      *(uint2*)(A + (nt * 16 + m) * STR + mt * 16 + quad * 4) = p;
    }
  }
  __syncthreads();
}

__global__ __launch_bounds__(256) void edge_inner_kernel(
    const float* __restrict__ x, const int* __restrict__ srcs, const int* __restrict__ dsts,
    const float* __restrict__ ws, float* __restrict__ yacc) {
  __shared__ unsigned short act[4][64 * STR];
  __shared__ int sdst[256];
  const int tid = threadIdx.x;
  const int w = tid >> 6;
  const int lane = tid & 63;
  unsigned short* A = act[w];

  const int pos = blockIdx.x * 256 + tid;  // E_N % 256 == 0
  const int src = srcs[pos];
  const int dst = dsts[pos];
  sdst[tid] = dst;

  const float4* x4 = (const float4*)x;
  float4 xi0 = x4[dst * 4 + 0], xi1 = x4[dst * 4 + 1], xi2 = x4[dst * 4 + 2], xi3 = x4[dst * 4 + 3];
  float4 xj0 = x4[src * 4 + 0], xj1 = x4[src * 4 + 1], xj2 = x4[src * 4 + 2], xj3 = x4[src * 4 + 3];
  float vi[16] = {xi0.x, xi0.y, xi0.z, xi0.w, xi1.x, xi1.y, xi1.z, xi1.w,
                  xi2.x, xi2.y, xi2.z, xi2.w, xi3.x, xi3.y, xi3.z, xi3.w};
  float vj[16] = {xj0.x, xj0.y, xj0.z, xj0.w, xj1.x, xj1.y, xj1.z, xj1.w,
                  xj2.x, xj2.y, xj2.z, xj2.w, xj3.x, xj3.y, xj3.z, xj3.w};
  unsigned int* row = (unsigned int*)(A + lane * STR);
#pragma unroll
  for (int q = 0; q < 8; ++q) row[q] = pack2(vi[2 * q], vi[2 * q + 1]);
#pragma unroll
  for (int q = 0; q < 8; ++q)
    row[8 + q] = pack2(vj[2 * q] - vi[2 * q], vj[2 * q + 1] - vi[2 * q + 1]);
  __syncthreads();

  const unsigned short* fr0 = (const unsigned short*)(ws + OFF_FR0);
  const unsigned short* fr1 = (const unsigned short*)(ws + OFF_FR1);
  const unsigned short* fr2 = (const unsigned short*)(ws + OFF_FR2);
  mfma_layer<1>(A, fr0, ws + OFF_B0F, lane);
  mfma_layer<2>(A, fr1, ws + OFF_B1F, lane);
  mfma_layer<2>(A, fr2, ws + OFF_B2F, lane);

  // segment-reduce the wave's 64 sorted edges: one atomic row per dst-run
  const int base = w << 6;
  float sum = 0.f;
  int dprev = sdst[base];
  for (int eo = 0; eo < 64; ++eo) {
    int d = sdst[base + eo];  // wave-uniform
    if (d != dprev) {
      atomicAdd(&yacc[(size_t)dprev * 64 + lane], sum);
      sum = 0.f;
      dprev = d;
    }
    sum += b2f(A[eo * STR + lane]);
  }
  atomicAdd(&yacc[(size_t)dprev * 64 + lane], sum);
}

__global__ __launch_bounds__(256) void node_kernel(
    const float* __restrict__ yacc, const int* __restrict__ counts,
    const float* __restrict__ x, unsigned short* __restrict__ ybf) {
  int idx = blockIdx.x * 256 + threadIdx.x;
  if (idx >= N_N * 80) return;
  int n = idx / 80;
  int j = idx - n * 80;
  float v;
  if (j < 64) v = yacc[(size_t)n * 64 + j] / fmaxf((float)counts[n], 1.0f);
  else        v = x[n * 16 + (j - 64)];
  ybf[idx] = f2b(fmaxf(v, 0.f));
}

// MFMA end-MLP in sorted order; writes pre-sigmoid z coalesced to zperm
__global__ __launch_bounds__(256) void edge_out_kernel(
    const unsigned short* __restrict__ ybf,
    const int* __restrict__ srcs, const int* __restrict__ dsts,
    const unsigned short* __restrict__ fe0, const float* __restrict__ bee0,
    const float* __restrict__ we1, const float* __restrict__ bee1,
    float* __restrict__ zperm) {
  __shared__ unsigned short Dt[4][64 * OSTR];
  const int tid = threadIdx.x, w = tid >> 6, lane = tid & 63;
  const int quad = lane >> 4, m = lane & 15;
  unsigned short* Dw = Dt[w];
  const int pos = blockIdx.x * 256 + tid;
  const int src = srcs[pos], dst = dsts[pos];
  const bf16x8* ps = (const bf16x8*)(ybf + (size_t)src * 80);
  const bf16x8* pd = (const bf16x8*)(ybf + (size_t)dst * 80);
  uint4* drow = (uint4*)(Dw + lane * OSTR);
#pragma unroll
  for (int q = 0; q < 10; ++q) {  // 80 feats = 10 bf16x8 loads
    bf16x8 a = ps[q], b = pd[q];
    uint4 p;
    p.x = pack2(b2f((unsigned short)a[0]) - b2f((unsigned short)b[0]),
                b2f((unsigned short)a[1]) - b2f((unsigned short)b[1]));
    p.y = pack2(b2f((unsigned short)a[2]) - b2f((unsigned short)b[2]),
                b2f((unsigned short)a[3]) - b2f((unsigned short)b[3]));
    p.z = pack2(b2f((unsigned short)a[4]) - b2f((unsigned short)b[4]),
                b2f((unsigned short)a[5]) - b2f((unsigned short)b[5]));
    p.w = pack2(b2f((unsigned short)a[6]) - b2f((unsigned short)b[6]),
                b2f((unsigned short)a[7]) - b2f((unsigned short)b[7]));
    drow[q] = p;
  }
  { uint4 z; z.x = z.y = z.z = z.w = 0u; drow[10] = z; drow[11] = z; }  // pad k=80..95
  __syncthreads();

  bf16x8 bf[4][3];
#pragma unroll
  for (int nt = 0; nt < 4; ++nt)
#pragma unroll
    for (int ks = 0; ks < 3; ++ks)
      bf[nt][ks] = *(const bf16x8*)(Dw + (nt * 16 + m) * OSTR + ks * 32 + quad * 8);

  float fin[4] = {0.f, 0.f, 0.f, 0.f};
  for (int mt = 0; mt < 8; ++mt) {
    bf16x8 wf[3];
#pragma unroll
    for (int ks = 0; ks < 3; ++ks)
      wf[ks] = *(const bf16x8*)(fe0 + (size_t)(((mt * 3 + ks) * 64) + lane) * 8);
    f32x4 binit = *(const f32x4*)(bee0 + mt * 16 + quad * 4);
    float4 w1v = *(const float4*)(we1 + mt * 16 + quad * 4);
    f32x4 acc[4];
#pragma unroll
    for (int nt = 0; nt < 4; ++nt) acc[nt] = binit;
#pragma unroll
    for (int nt = 0; nt < 4; ++nt)
#pragma unroll
      for (int ks = 0; ks < 3; ++ks)
        acc[nt] = __builtin_amdgcn_mfma_f32_16x16x32_bf16(wf[ks], bf[nt][ks], acc[nt], 0, 0, 0);
#pragma unroll
    for (int nt = 0; nt < 4; ++nt) {
      f32x4 a = acc[nt];
      fin[nt] += fmaxf(a.x, 0.f) * w1v.x + fmaxf(a.y, 0.f) * w1v.y +
                 fmaxf(a.z, 0.f) * w1v.z + fmaxf(a.w, 0.f) * w1v.w;
    }
  }
#pragma unroll
  for (int nt = 0; nt < 4; ++nt) {
    float v = fin[nt];
    v += __shfl_xor(v, 16);
    v += __shfl_xor(v, 32);
    fin[nt] = v;
  }
  float z = (quad == 0) ? fin[0] : (quad == 1) ? fin[1] : (quad == 2) ? fin[2] : fin[3];
  zperm[pos] = z + bee1[0];
}

__global__ __launch_bounds__(256) void unperm_kernel(const float* __restrict__ zperm,
                                                     const int* __restrict__ ipos,
                                                     float* __restrict__ out) {
  int e = blockIdx.x * 256 + threadIdx.x;
  if (e >= E_N) return;
  float z = zperm[ipos[e]];
  out[e] = 1.0f / (1.0f + __expf(-z));
}

extern "C" void kernel_launch(void* const* d_in, const int* in_sizes, int n_in,
                              void* d_out, int out_size, void* d_ws, size_t ws_size,
                              hipStream_t stream) {
  const float* x   = (const float*)d_in[0];
  const int* ei    = (const int*)d_in[1];
  const float* w0  = (const float*)d_in[2];
  const float* b0  = (const float*)d_in[3];
  const float* g0  = (const float*)d_in[4];
  const float* be0 = (const float*)d_in[5];
  const float* m0  = (const float*)d_in[6];
  const float* v0  = (const float*)d_in[7];
  const float* w1  = (const float*)d_in[8];
  const float* b1  = (const float*)d_in[9];
  const float* g1  = (const float*)d_in[10];
  const float* be1 = (const float*)d_in[11];
  const float* m1  = (const float*)d_in[12];
  const float* v1  = (const float*)d_in[13];
  const float* w2  = (const float*)d_in[14];
  const float* b2  = (const float*)d_in[15];
  const float* g2  = (const float*)d_in[16];
  const float* be2 = (const float*)d_in[17];
  const float* m2  = (const float*)d_in[18];
  const float* v2  = (const float*)d_in[19];
  const float* we0 = (const float*)d_in[20];
  const float* bee0= (const float*)d_in[21];
  const float* we1 = (const float*)d_in[22];
  const float* bee1= (const float*)d_in[23];
  float* out = (float*)d_out;
  float* ws  = (float*)d_ws;

  int* counts = (int*)(ws + OFF_CNT);
  int* cursor = (int*)(ws + OFF_CUR);
  int* bsum   = (int*)(ws + OFF_BSUM);
  int* srcs   = (int*)(ws + OFF_SRCS);
  int* dsts   = (int*)(ws + OFF_DSTS);
  int* ipos   = (int*)(ws + OFF_IPOS);
  float* zperm = ws + OFF_YACC;  // aliases yacc: dead after node_kernel

  hipMemsetAsync(ws + OFF_YACC, 0, (size_t)N_N * 64 * sizeof(float), stream);
  hipMemsetAsync(counts, 0, (size_t)N_N * sizeof(int), stream);
  prep_kernel<<<1, 256, 0, stream>>>(w0, b0, g0, be0, m0, v0,
                                     w1, b1, g1, be1, m1, v1,
                                     w2, b2, g2, be2, m2, v2, we0, ws);
  hist_kernel<<<(E_N + 255) / 256, 256, 0, stream>>>(ei, counts);
  scan1_kernel<<<SCAN_B, 1024, 0, stream>>>(counts, cursor, bsum);
  scan2_kernel<<<1, 128, 0, stream>>>(bsum);
  scan3_kernel<<<SCAN_B, 1024, 0, stream>>>(cursor, bsum);
  scatter_kernel<<<(E_N + 255) / 256, 256, 0, stream>>>(ei, cursor, srcs, dsts, ipos);
  edge_inner_kernel<<<E_N / 256, 256, 0, stream>>>(x, srcs, dsts, ws, ws + OFF_YACC);
  node_kernel<<<(N_N * 80 + 255) / 256, 256, 0, stream>>>(ws + OFF_YACC, counts, x,
                                                          (unsigned short*)(ws + OFF_YBF));
  edge_out_kernel<<<E_N / 256, 256, 0, stream>>>((const unsigned short*)(ws + OFF_YBF),
                                                 srcs, dsts,
                                                 (const unsigned short*)(ws + OFF_FE0),
                                                 bee0, we1, bee1, zperm);
  unperm_kernel<<<(E_N + 255) / 256, 256, 0, stream>>>(zperm, ipos, out);
}